// Round 3
// baseline (8832.691 us; speedup 1.0000x reference)
//
#include <hip/hip_runtime.h>
#include <cstdint>

#define VOCAB 50257
#define VTOT  50321
#define TDEC  100
#define UNK   3
#define NBLK  256          // persistent decode blocks (1 per CU; all co-resident)
#define NTHR  512
#define VPB   256          // vocab rows per block (197 blocks cover 50432 >= 50321)
#define VPAD  50304        // W_T column stride (786*64, 256B-aligned columns)

// ---------------- workspace layout (float offsets) ----------------
static const size_t OFF_EMB    = 0;        // [1024][128]
static const size_t OFF_WIHT_F = 131072;   // [128][640]
static const size_t OFF_WIHT_B = 212992;   // [128][640]
static const size_t OFF_WTE    = 294912;   // [320][320]
static const size_t OFF_XG     = 397312;   // [2][1024][640]
static const size_t OFF_ENCH   = 1708032;  // [1024][320]
static const size_t OFF_EPH    = 2035712;  // [1024][320]
static const size_t OFF_DECBUF = 2363392;  // [100][320] (private to block 16)
static const size_t OFF_GATES  = 2395392;  // 1280
static const size_t OFF_HPAR   = 2396672;  // [8][320]
static const size_t OFF_CPAR   = 2399232;  // [16][320]
static const size_t OFF_DCTX   = 2404352;  // 320
static const size_t OFF_H0     = 2404672;  // 320
static const size_t OFF_TEMP   = 2404992;  // 1024 temporal values
static const size_t OFF_ATTN   = 2406016;  // 1024
static const size_t OFF_PMS    = 2407040;  // [256][2] attn softmax partials
static const size_t OFF_BM     = 2407552;  // 256
static const size_t OFF_BS     = 2407808;  // 256
static const size_t OFF_AVAL   = 2408064;  // 256
static const size_t OFF_AIDX   = 2408320;  // 256 (int)
static const size_t OFF_BAR    = 2408576;  // int[64]: [0]=count, [32]=generation
static const size_t OFF_SKEY   = 2408640;  // 1024 (int)
static const size_t OFF_SPOS   = 2409664;  // 1024 (int)
static const size_t OFF_BSTART = 2410688;  // 264 (int)
static const size_t OFF_WT     = 2411008;  // W_T: u32[480][VPAD] bf16-pairs, 96.6 MB

__device__ __forceinline__ float sigmf(float x) { return 1.f / (1.f + expf(-x)); }

__device__ __forceinline__ float wsum64(float x) {
#pragma unroll
  for (int m = 1; m < 64; m <<= 1) x += __shfl_xor(x, m, 64);
  return x;
}

__device__ __forceinline__ unsigned short bf16r(float x) {
  uint32_t b = __float_as_uint(x);
  uint32_t r = (b + 0x7fffu + ((b >> 16) & 1u)) >> 16;
  return (unsigned short)r;
}

// coherent (fabric-point) accessors: bypass L1/L2, per-word coherent across XCDs
__device__ __forceinline__ float cload(const float* p) {
  return __hip_atomic_load((float*)p, __ATOMIC_RELAXED, __HIP_MEMORY_SCOPE_AGENT);
}
__device__ __forceinline__ void cstore(float* p, float v) {
  __hip_atomic_store(p, v, __ATOMIC_RELAXED, __HIP_MEMORY_SCOPE_AGENT);
}
__device__ __forceinline__ int cloadi(const int* p) {
  return __hip_atomic_load((int*)p, __ATOMIC_RELAXED, __HIP_MEMORY_SCOPE_AGENT);
}
__device__ __forceinline__ void cstorei(int* p, int v) {
  __hip_atomic_store(p, v, __ATOMIC_RELAXED, __HIP_MEMORY_SCOPE_AGENT);
}

// device-wide barrier, zero cache maintenance (all shared data moves coherently)
__device__ __forceinline__ void gridbar(float* ws) {
  int* bar = (int*)(ws + OFF_BAR);
  __syncthreads();   // each wave drains vmcnt before s_barrier -> cstores visible
  if (threadIdx.x == 0) {
    asm volatile("s_waitcnt vmcnt(0) lgkmcnt(0)" ::: "memory");
    int g = __hip_atomic_load(&bar[32], __ATOMIC_RELAXED, __HIP_MEMORY_SCOPE_AGENT);
    int old = __hip_atomic_fetch_add(&bar[0], 1, __ATOMIC_RELAXED, __HIP_MEMORY_SCOPE_AGENT);
    if (old == NBLK - 1) {
      __hip_atomic_store(&bar[0], 0, __ATOMIC_RELAXED, __HIP_MEMORY_SCOPE_AGENT);
      __hip_atomic_store(&bar[32], g + 1, __ATOMIC_RELAXED, __HIP_MEMORY_SCOPE_AGENT);
    } else {
      while (__hip_atomic_load(&bar[32], __ATOMIC_RELAXED, __HIP_MEMORY_SCOPE_AGENT) == g)
        __builtin_amdgcn_s_sleep(2);
    }
  }
  __syncthreads();
}

// ---------------- P1: gather embeddings, transposes ----------------
__global__ __launch_bounds__(256) void k_setup(float* __restrict__ ws, const int* __restrict__ ids,
                                               const float* __restrict__ embt, const float* __restrict__ ewf,
                                               const float* __restrict__ ewb, const float* __restrict__ eap) {
  int idx = blockIdx.x * 256 + threadIdx.x;
  if (idx < 131072) {
    int tt = idx >> 7, e = idx & 127;
    int id = ids[tt]; if (id >= VOCAB) id = UNK;
    ws[OFF_EMB + idx] = embt[(size_t)id * 128 + e];
  } else if (idx < 212992) {
    int i = idx - 131072;
    int k = i / 640, g = i - (i / 640) * 640;
    ws[OFF_WIHT_F + i] = ewf[(size_t)g * 128 + k];
  } else if (idx < 294912) {
    int i = idx - 212992;
    int k = i / 640, g = i - (i / 640) * 640;
    ws[OFF_WIHT_B + i] = ewb[(size_t)g * 128 + k];
  } else if (idx < 397312) {
    int i = idx - 294912;
    int k = i / 320, j = i - (i / 320) * 320;
    ws[OFF_WTE + i] = eap[(size_t)j * 320 + k];
  }
}

// ---------------- P2: encoder x-part gates ----------------
__global__ __launch_bounds__(256) void k_xg(float* __restrict__ ws,
                                            const float* __restrict__ bif, const float* __restrict__ bhf,
                                            const float* __restrict__ bib, const float* __restrict__ bhb) {
  int idx = blockIdx.x * 256 + threadIdx.x;
  int d = idx / 655360;
  int r = idx - d * 655360;
  int tt = r / 640, g = r - (r / 640) * 640;
  const float* wT = ws + (d ? OFF_WIHT_B : OFF_WIHT_F);
  const float* er = ws + OFF_EMB + (size_t)(d ? (1023 - tt) : tt) * 128;
  float acc = d ? (bib[g] + bhb[g]) : (bif[g] + bhf[g]);
#pragma unroll 4
  for (int k = 0; k < 128; ++k) acc += er[k] * wT[(size_t)k * 640 + g];
  ws[OFF_XG + idx] = acc;
}

// ---------------- P3: W_T = bf16(tanh(embedding @ vocab_proj)) transposed ----------------
// W_T[fp][v] (u32, packs features 2fp,2fp+1) with column stride VPAD -> phase-D
// GEMV reads are lane-coalesced (consecutive lanes = consecutive vocab rows).
__global__ __launch_bounds__(256) void k_outproj(const float* __restrict__ embt, const float* __restrict__ vp,
                                                 float* __restrict__ ws) {
  __shared__ float As[64][128];
  __shared__ float Bs[128][64];
  __shared__ unsigned T[32][64];
  const int tid = threadIdx.x;
  const int v0 = blockIdx.x * 64, n0 = blockIdx.y * 64;
  for (int c = 0; c < 32; ++c) {
    int idx = c * 256 + tid;
    int m = idx >> 7, k = idx & 127;
    int v = v0 + m;
    As[m][k] = (v < VOCAB) ? embt[(size_t)v * 128 + k] : 0.f;
    int k2 = idx >> 6, n = idx & 63;
    Bs[k2][n] = vp[(size_t)k2 * 960 + n0 + n];
  }
  __syncthreads();
  const int mi = tid >> 4, ni = tid & 15;
  float acc[4][4] = {};
  for (int k = 0; k < 128; ++k) {
    float a0 = As[mi * 4 + 0][k], a1 = As[mi * 4 + 1][k], a2 = As[mi * 4 + 2][k], a3 = As[mi * 4 + 3][k];
    float4 b = *(const float4*)&Bs[k][ni * 4];
    acc[0][0] += a0 * b.x; acc[0][1] += a0 * b.y; acc[0][2] += a0 * b.z; acc[0][3] += a0 * b.w;
    acc[1][0] += a1 * b.x; acc[1][1] += a1 * b.y; acc[1][2] += a1 * b.z; acc[1][3] += a1 * b.w;
    acc[2][0] += a2 * b.x; acc[2][1] += a2 * b.y; acc[2][2] += a2 * b.z; acc[2][3] += a2 * b.w;
    acc[3][0] += a3 * b.x; acc[3][1] += a3 * b.y; acc[3][2] += a3 * b.z; acc[3][3] += a3 * b.w;
  }
  // stage packed bf16-pairs into LDS transposed tile: T[fp_local][row_local]
#pragma unroll
  for (int i = 0; i < 4; ++i) {
    unsigned p0 = (unsigned)bf16r(tanhf(acc[i][0])) | ((unsigned)bf16r(tanhf(acc[i][1])) << 16);
    unsigned p1 = (unsigned)bf16r(tanhf(acc[i][2])) | ((unsigned)bf16r(tanhf(acc[i][3])) << 16);
    T[2 * ni][mi * 4 + i] = p0;
    T[2 * ni + 1][mi * 4 + i] = p1;
  }
  __syncthreads();
  unsigned* WT = (unsigned*)(ws + OFF_WT);
  const int kbase = n0 >> 1;
#pragma unroll
  for (int r = 0; r < 8; ++r) {
    int idx = r * 256 + tid;
    int fp = idx >> 6, col = idx & 63;
    int v = v0 + col;
    if (v < VOCAB) WT[(size_t)(kbase + fp) * VPAD + v] = T[fp][col];
  }
}

// ---------------- P4: sequential bi-LSTM encoder ----------------
__global__ __launch_bounds__(512) void k_encoder(float* __restrict__ ws, const float* __restrict__ whh_f,
                                                 const float* __restrict__ whh_b) {
  const int dir = blockIdx.x;
  const int tid = threadIdx.x;
  const float* whh = dir ? whh_b : whh_f;
  const float* xg = ws + OFF_XG + (size_t)dir * 655360;
  __shared__ float hbuf[160];
  __shared__ float part[4][640];
  const int q = tid & 127, kg = tid >> 7, ks = kg * 40;
  float w[5][40];
#pragma unroll
  for (int j = 0; j < 5; ++j)
#pragma unroll
    for (int i = 0; i < 40; ++i)
      w[j][i] = whh[(size_t)(5 * q + j) * 160 + ks + i];
  float cst = 0.f;
  if (tid < 160) hbuf[tid] = 0.f;
  __syncthreads();
  for (int t = 0; t < 1024; ++t) {
    float acc[5] = {0.f, 0.f, 0.f, 0.f, 0.f};
#pragma unroll
    for (int i4 = 0; i4 < 10; ++i4) {
      float4 h4 = *(const float4*)&hbuf[ks + i4 * 4];
#pragma unroll
      for (int j = 0; j < 5; ++j)
        acc[j] += w[j][i4 * 4 + 0] * h4.x + w[j][i4 * 4 + 1] * h4.y + w[j][i4 * 4 + 2] * h4.z + w[j][i4 * 4 + 3] * h4.w;
    }
#pragma unroll
    for (int j = 0; j < 5; ++j) part[kg][5 * q + j] = acc[j];
    __syncthreads();
    if (tid < 160) {
      float gi = xg[(size_t)t * 640 + tid];
      float gf = xg[(size_t)t * 640 + 160 + tid];
      float gg = xg[(size_t)t * 640 + 320 + tid];
      float go = xg[(size_t)t * 640 + 480 + tid];
#pragma unroll
      for (int k2 = 0; k2 < 4; ++k2) {
        gi += part[k2][tid]; gf += part[k2][160 + tid];
        gg += part[k2][320 + tid]; go += part[k2][480 + tid];
      }
      cst = sigmf(gf) * cst + sigmf(gi) * tanhf(gg);
      float hn = sigmf(go) * tanhf(cst);
      hbuf[tid] = hn;
      int trow = dir ? (1023 - t) : t;
      ws[OFF_ENCH + (size_t)trow * 320 + dir * 160 + tid] = hn;
    }
    __syncthreads();
  }
  if (tid < 160) ws[OFF_H0 + dir * 160 + tid] = hbuf[tid];
}

// ---------------- P5: enc_proj_h ----------------
__global__ __launch_bounds__(256) void k_encproj(float* __restrict__ ws) {
  int idx = blockIdx.x * 256 + threadIdx.x;
  int s = idx / 320, j = idx - (idx / 320) * 320;
  const float* er = ws + OFF_ENCH + (size_t)s * 320;
  const float* wt = ws + OFF_WTE;
  float acc = 0.f;
#pragma unroll 4
  for (int k = 0; k < 320; ++k) acc += er[k] * wt[(size_t)k * 320 + j];
  ws[OFF_EPH + idx] = acc;
}

// ---------------- P6: sort ids + slice table + barrier init ----------------
__global__ __launch_bounds__(512) void k_sort(float* __restrict__ ws, const int* __restrict__ ids) {
  __shared__ int sk[1024], sp[1024];
  const int tid = threadIdx.x;
  for (int j = tid; j < 1024; j += 512) { sk[j] = ids[j]; sp[j] = j; }
  __syncthreads();
  for (int k = 2; k <= 1024; k <<= 1)
    for (int j = k >> 1; j > 0; j >>= 1) {
      for (int i = tid; i < 1024; i += 512) {
        int ixj = i ^ j;
        if (ixj > i) {
          bool up = ((i & k) == 0);
          int a = sk[i], b2 = sk[ixj];
          if (up ? (a > b2) : (a < b2)) {
            sk[i] = b2; sk[ixj] = a;
            int pa = sp[i]; sp[i] = sp[ixj]; sp[ixj] = pa;
          }
        }
      }
      __syncthreads();
    }
  int* BST = (int*)(ws + OFF_BSTART);
  int* SK = (int*)(ws + OFF_SKEY);
  int* SP = (int*)(ws + OFF_SPOS);
  for (int j = tid; j < 1024; j += 512) {
    SK[j] = sk[j]; SP[j] = sp[j];
    int o1 = sk[j] / VPB;
    int o0 = (j == 0) ? -1 : (sk[j - 1] / VPB);
    for (int o = o0 + 1; o <= o1; ++o) BST[o] = j;
  }
  if (tid == 0) {
    int olast = sk[1023] / VPB;
    for (int o = olast + 1; o <= NBLK; ++o) BST[o] = 1024;
    int* bar = (int*)(ws + OFF_BAR);
    bar[0] = 0; bar[32] = 0;
  }
}

// ---------------- persistent decode: all 100 steps in one kernel ----------------
__global__ __launch_bounds__(512) void k_decode(float* __restrict__ ws, float* __restrict__ out,
    const float* __restrict__ embt,
    const float* __restrict__ dwih, const float* __restrict__ dwhh,
    const float* __restrict__ dbih, const float* __restrict__ dbhh,
    const float* __restrict__ dap, const float* __restrict__ sw,
    const float* __restrict__ sb, const float* __restrict__ ob) {
  const int b = blockIdx.x, tid = threadIdx.x;
  const int l = tid & 63, w = tid >> 6;
  __shared__ __align__(16) float hL[320];
  __shared__ float cL[320];
  __shared__ __align__(16) float concatL[960];
  __shared__ float logitsL[VPB];
  __shared__ float tauL[4], cumL[4];
  __shared__ float redA[512], redB[512];
  __shared__ int   redI[512];
  __shared__ float attnL[64], dsL[128], daL[128], hpL[320];
  __shared__ float pcS;

  const int vrow = b * VPB + (int)tid;          // this thread's vocab row
  const bool myrow = (tid < VPB) && (vrow < VOCAB);
  const unsigned* WT = (const unsigned*)(ws + OFF_WT);

  if (tid < 320) { hL[tid] = ws[OFF_H0 + tid]; cL[tid] = 0.f; }
  if (tid < 4) cumL[tid] = 0.f;
  __syncthreads();

  for (int t = 0; t < TDEC; ++t) {
    // ======= phase A: token argmax (replicated) + gate rows (5 per block) =======
    int token = 0;
    if (t > 0) {
      float av = -1e30f; int ai = 0;
      if (tid < 256) { av = cload(&ws[OFF_AVAL + tid]); ai = cloadi(((const int*)(ws + OFF_AIDX)) + tid); }
      redA[tid] = av; redI[tid] = ai;
      __syncthreads();
      for (int off = 256; off > 0; off >>= 1) {
        if (tid < off) {
          float v2 = redA[tid + off]; int i2 = redI[tid + off];
          if (v2 > redA[tid] || (v2 == redA[tid] && i2 < redI[tid])) { redA[tid] = v2; redI[tid] = i2; }
        }
        __syncthreads();
      }
      token = redI[0];
    }
    int tokm = (token >= VOCAB) ? UNK : token;
    if (w < 5) {  // rows 5b..5b+4 of the 1280 gates, one per warp
      const int r = 5 * b + w;
      float acc = dwih[(size_t)r * 128 + l] * embt[(size_t)tokm * 128 + l]
                + dwih[(size_t)r * 128 + 64 + l] * embt[(size_t)tokm * 128 + 64 + l];
#pragma unroll
      for (int c = 0; c < 5; ++c) acc += dwhh[(size_t)r * 320 + c * 64 + l] * hL[c * 64 + l];
      acc = wsum64(acc);
      if (l == 0) cstore(&ws[OFF_GATES + r], acc + dbih[r] + dbhh[r]);
    }
    gridbar(ws);

    // ======= phase B: replicated h,c + score rows + hpar partials =======
    if (tid < 320) {
      float gi = cload(&ws[OFF_GATES + tid]);
      float gf = cload(&ws[OFF_GATES + 320 + tid]);
      float gg = cload(&ws[OFF_GATES + 640 + tid]);
      float go = cload(&ws[OFF_GATES + 960 + tid]);
      float c = sigmf(gf) * cL[tid] + sigmf(gi) * tanhf(gg);
      cL[tid] = c;
      float hn = sigmf(go) * tanhf(c);
      hL[tid] = hn;
      if (b == 16) ws[OFF_DECBUF + (size_t)t * 320 + tid] = hn;  // private to block 16
    }
    __syncthreads();
    if (w < 4) {  // score rows 4b..4b+3
      const int srow = 4 * b + w;
      const float* er = ws + OFF_EPH + (size_t)srow * 320;
      float acc = 0.f;
#pragma unroll
      for (int c = 0; c < 5; ++c) acc += er[c * 64 + l] * hL[c * 64 + l];
      acc = wsum64(acc);
      float tau = (t == 0) ? acc : expf(acc) / cumL[w];
      if (l == 0) {
        tauL[w] = tau;
        cstore(&ws[OFF_TEMP + srow], tau);
        cumL[w] += acc;
      }
    }
    if (b < 8 && tid < 320) {  // hpar partials (split over inner dim, 8 x 40)
      float acc = 0.f;
#pragma unroll 8
      for (int ii = 0; ii < 40; ++ii) {
        int i = b * 40 + ii;
        acc += hL[i] * dap[(size_t)i * 320 + tid];
      }
      cstore(&ws[OFF_HPAR + b * 320 + tid], acc);
    }
    __syncthreads();
    if (tid == 0) {
      float m4 = fmaxf(fmaxf(tauL[0], tauL[1]), fmaxf(tauL[2], tauL[3]));
      float s4 = expf(tauL[0] - m4) + expf(tauL[1] - m4) + expf(tauL[2] - m4) + expf(tauL[3] - m4);
      cstore(&ws[OFF_PMS + 2 * b], m4);
      cstore(&ws[OFF_PMS + 2 * b + 1], s4);
    }
    gridbar(ws);

    // ======= phase C: attn/ctx (blocks 0..16) overlapped with h-part GEMV (all) =======
    if (b < 16) {
      float m = -1e30f, s = 0.f;
      if (tid < 256) { m = cload(&ws[OFF_PMS + 2 * tid]); s = cload(&ws[OFF_PMS + 2 * tid + 1]); }
      redA[tid] = m; redB[tid] = s;
      __syncthreads();
      for (int off = 256; off > 0; off >>= 1) {
        if (tid < off) {
          float m1 = redA[tid], m2 = redA[tid + off];
          float mx = fmaxf(m1, m2);
          redB[tid] = redB[tid] * expf(m1 - mx) + redB[tid + off] * expf(m2 - mx);
          redA[tid] = mx;
        }
        __syncthreads();
      }
      const float M = redA[0], S = redB[0];
      __syncthreads();
      if (tid < 64) {
        float a = expf(cload(&ws[OFF_TEMP + 64 * b + tid]) - M) / S;
        attnL[tid] = a;
        cstore(&ws[OFF_ATTN + 64 * b + tid], a);
      }
      __syncthreads();
      if (tid < 320) {
        float acc = 0.f;
        const float* eh = ws + OFF_ENCH + (size_t)(64 * b) * 320 + tid;
#pragma unroll 4
        for (int k2 = 0; k2 < 64; ++k2) acc += attnL[k2] * eh[(size_t)k2 * 320];
        cstore(&ws[OFF_CPAR + b * 320 + tid], acc);
      }
    } else if (b == 16) {
      if (tid < 320) {
        float a = 0.f;
#pragma unroll
        for (int q = 0; q < 8; ++q) a += cload(&ws[OFF_HPAR + q * 320 + tid]);
        hpL[tid] = a;
      }
      __syncthreads();
      float hpv[5];
#pragma unroll
      for (int c = 0; c < 5; ++c) hpv[c] = hpL[c * 64 + l];
#pragma unroll
      for (int k2 = 0; k2 < 13; ++k2) {
        int tp = w + 8 * k2;
        if (tp < t) {
          float acc = 0.f;
#pragma unroll
          for (int c = 0; c < 5; ++c) acc += hpv[c] * ws[OFF_DECBUF + (size_t)tp * 320 + c * 64 + l];
          acc = wsum64(acc);
          if (l == 0) dsL[tp] = acc;
        }
      }
      __syncthreads();
      float dv = -1e30f;
      if (tid < 128) { dv = (tid < t) ? dsL[tid] : -1e30f; redA[tid] = dv; }
      __syncthreads();
      for (int off = 64; off > 0; off >>= 1) { if (tid < off) redA[tid] = fmaxf(redA[tid], redA[tid + off]); __syncthreads(); }
      float dmx = redA[0];
      __syncthreads();
      float de = (tid < 128) ? expf(dv - dmx) : 0.f;
      if (tid < 128) redA[tid] = de;
      __syncthreads();
      for (int off = 64; off > 0; off >>= 1) { if (tid < off) redA[tid] += redA[tid + off]; __syncthreads(); }
      float dS = redA[0];
      __syncthreads();
      if (tid < 128) daL[tid] = de / dS;
      __syncthreads();
      if (tid < 320) {
        float acc = 0.f;
        for (int tp = 0; tp < t; ++tp) acc += daL[tp] * ws[OFF_DECBUF + (size_t)tp * 320 + tid];
        cstore(&ws[OFF_DCTX + tid], (t == 0) ? 0.f : acc);
      }
    }
    // h-part of the logits GEMV (k<160 only needs h, available now): thread-per-row,
    // fully independent coalesced loads — overlaps with blocks 0..16's attention work.
    float ga0 = 0.f, ga1 = 0.f, ga2 = 0.f, ga3 = 0.f;
    if (myrow) {
      const unsigned* wp = WT + vrow;
#pragma unroll 8
      for (int k = 0; k < 160; ++k) {
        unsigned u = wp[(size_t)k * VPAD];
        float2 cv = *(const float2*)&hL[2 * k];
        ga0 += __uint_as_float(u << 16) * cv.x;
        ga1 += __uint_as_float(u & 0xffff0000u) * cv.y;
      }
    }
    gridbar(ws);

    // ======= phase D: concat + p_copy + remaining GEMV + block softmax partial =======
    if (tid < 320) {
      float e = 0.f;
#pragma unroll
      for (int g2 = 0; g2 < 16; ++g2) e += cload(&ws[OFF_CPAR + g2 * 320 + tid]);
      concatL[tid] = hL[tid];
      concatL[320 + tid] = e;
      concatL[640 + tid] = cload(&ws[OFF_DCTX + tid]);
    }
    __syncthreads();
    if (w == 0) {
      float acc = 0.f;
#pragma unroll
      for (int c = 0; c < 15; ++c) acc += sw[c * 64 + l] * concatL[c * 64 + l];
      acc = wsum64(acc);
      if (l == 0) pcS = 1.f / (1.f + expf(-(acc + sb[0])));
    }
    if (myrow) {
      const unsigned* wp = WT + vrow;
#pragma unroll 8
      for (int k = 160; k < 480; ++k) {
        unsigned u = wp[(size_t)k * VPAD];
        float2 cv = *(const float2*)&concatL[2 * k];
        ga2 += __uint_as_float(u << 16) * cv.x;
        ga3 += __uint_as_float(u & 0xffff0000u) * cv.y;
      }
    }
    if (tid < VPB) logitsL[tid] = myrow ? (ga0 + ga1 + ga2 + ga3 + ob[vrow]) : -1e30f;
    __syncthreads();
    {
      float m = -1e30f, s = 0.f;
      if (tid < VPB) { float lv = logitsL[tid]; if (lv > -1e29f) { m = lv; s = 1.f; } }
      redA[tid] = m; redB[tid] = s;
      __syncthreads();
      for (int off = 256; off > 0; off >>= 1) {
        if (tid < off) {
          float m1 = redA[tid], m2 = redA[tid + off];
          float mx = fmaxf(m1, m2);
          redB[tid] = redB[tid] * expf(m1 - mx) + redB[tid + off] * expf(m2 - mx);
          redA[tid] = mx;
        }
        __syncthreads();
      }
      if (tid == 0) { cstore(&ws[OFF_BM + b], redA[0]); cstore(&ws[OFF_BS + b], redB[0]); }
    }
    gridbar(ws);

    // ======= phase E: global softmax combine + final + scatter + argmax =======
    {
      float m = -1e30f, s = 0.f;
      if (tid < 256) { m = cload(&ws[OFF_BM + tid]); s = cload(&ws[OFF_BS + tid]); }
      redA[tid] = m; redB[tid] = s;
      __syncthreads();
      for (int off = 256; off > 0; off >>= 1) {
        if (tid < off) {
          float m1 = redA[tid], m2 = redA[tid + off];
          float mx = fmaxf(m1, m2);
          redB[tid] = redB[tid] * expf(m1 - mx) + redB[tid + off] * expf(m2 - mx);
          redA[tid] = mx;
        }
        __syncthreads();
      }
      const float M = redA[0], Sg = redB[0];
      const float pc = pcS;
      const float scale = (1.f - pc) / Sg;
      __syncthreads();
      const int* BST = (const int*)(ws + OFF_BSTART);
      const int* SK = (const int*)(ws + OFF_SKEY);
      const int* SP = (const int*)(ws + OFF_SPOS);
      int v = b * VPB + (int)tid;
      bool act = (tid < VPB) && (v < VTOT);
      float val = -1e30f;
      if (act) {
        val = (v < VOCAB) ? scale * expf(logitsL[tid] - M) : 0.f;
        int jb = BST[b], je = BST[b + 1];
        for (int j = jb; j < je; ++j)
          if (SK[j] == v) val += pc * cload(&ws[OFF_ATTN + SP[j]]);
        out[(size_t)t * VTOT + v] = val;
      }
      redA[tid] = act ? val : -1e30f; redI[tid] = v;
      __syncthreads();
      for (int off = 256; off > 0; off >>= 1) {
        if (tid < off) {
          float v2 = redA[tid + off]; int i2 = redI[tid + off];
          if (v2 > redA[tid] || (v2 == redA[tid] && i2 < redI[tid])) { redA[tid] = v2; redI[tid] = i2; }
        }
        __syncthreads();
      }
      if (tid == 0) { cstore(&ws[OFF_AVAL + b], redA[0]); cstorei(((int*)(ws + OFF_AIDX)) + b, redI[0]); }
    }
    gridbar(ws);
  }
}

// ---------------- host ----------------
extern "C" void kernel_launch(void* const* d_in, const int* in_sizes, int n_in,
                              void* d_out, int out_size, void* d_ws, size_t ws_size,
                              hipStream_t stream) {
  const int*   ids  = (const int*)d_in[0];
  const float* embt = (const float*)d_in[1];
  const float* ewf  = (const float*)d_in[2];
  const float* ehf  = (const float*)d_in[3];
  const float* ebif = (const float*)d_in[4];
  const float* ebhf = (const float*)d_in[5];
  const float* ewb  = (const float*)d_in[6];
  const float* ehb  = (const float*)d_in[7];
  const float* ebib = (const float*)d_in[8];
  const float* ebhb = (const float*)d_in[9];
  const float* dwih = (const float*)d_in[10];
  const float* dwhh = (const float*)d_in[11];
  const float* dbih = (const float*)d_in[12];
  const float* dbhh = (const float*)d_in[13];
  const float* eap  = (const float*)d_in[14];
  const float* dap  = (const float*)d_in[15];
  const float* vp   = (const float*)d_in[16];
  const float* ob   = (const float*)d_in[17];
  const float* sw   = (const float*)d_in[18];
  const float* sb   = (const float*)d_in[19];
  float* out = (float*)d_out;
  float* ws  = (float*)d_ws;

  k_setup<<<1558, 256, 0, stream>>>(ws, ids, embt, ewf, ewb, eap);
  k_xg<<<5120, 256, 0, stream>>>(ws, ebif, ebhf, ebib, ebhb);
  k_outproj<<<dim3(786, 15), 256, 0, stream>>>(embt, vp, ws);
  k_encoder<<<2, 512, 0, stream>>>(ws, ehf, ehb);
  k_encproj<<<1280, 256, 0, stream>>>(ws);
  k_sort<<<1, 512, 0, stream>>>(ws, ids);
  k_decode<<<NBLK, NTHR, 0, stream>>>(ws, out, embt, dwih, dwhh, dbih, dbhh, dap, sw, sb, ob);
}

// Round 4
// 8535.007 us; speedup vs baseline: 1.0349x; 1.0349x over previous
//
#include <hip/hip_runtime.h>
#include <cstdint>

#define VOCAB 50257
#define VTOT  50321
#define TDEC  100
#define UNK   3
#define NBLK  256          // persistent decode blocks
#define NTHR  512
#define VB0   17           // first vocab block
#define NVB   197          // vocab blocks: rows 256 each, 197*256=50432 >= VTOT
#define K4N   120          // uint4 elements per vocab row (120*16B = 480 u32 = 960 bf16)

// ---------------- workspace layout (float offsets) ----------------
// W_T lives at 0 and is written LAST among setup kernels (k_outproj), overlaying
// the dead setup-era arrays below it. Live decode data sits above W_T.
static const size_t OFF_WT     = 0;         // uint4[NVB][120][256] = 24,207,360 floats
static const size_t OFF_EMB    = 0;         // [1024][128]   (dead after k_xg)
static const size_t OFF_WIHT_F = 131072;    // [128][640]    (dead after k_xg)
static const size_t OFF_WIHT_B = 212992;    // [128][640]    (dead after k_xg)
static const size_t OFF_WTE    = 294912;    // [320][320]    (dead after k_encproj)
static const size_t OFF_XG     = 397312;    // [2][1024][640](dead after k_encoder)
static const size_t OFF_ENCH   = 24207360;  // [1024][320]
static const size_t OFF_EPH    = 24535040;  // [1024][320]
static const size_t OFF_DECBUF = 24862720;  // [100][320] (private to block 16)
static const size_t OFF_GATES  = 24894720;  // 1280
static const size_t OFF_HPAR   = 24896000;  // [8][320]
static const size_t OFF_CPAR   = 24898560;  // [16][320]
static const size_t OFF_DCTX   = 24903680;  // 320
static const size_t OFF_H0     = 24904000;  // 320
static const size_t OFF_TEMP   = 24904320;  // 1024
static const size_t OFF_ATTN   = 24905344;  // 1024
static const size_t OFF_PMS    = 24906368;  // [256][2]
static const size_t OFF_BM     = 24906880;  // 256
static const size_t OFF_BS     = 24907136;  // 256
static const size_t OFF_AVAL   = 24907392;  // 256
static const size_t OFF_AIDX   = 24907648;  // 256 (int)
static const size_t OFF_PC     = 24907904;  // 64 (use 1)
static const size_t OFF_BAR    = 24907968;  // int[64]: [0]=count, [32]=generation
static const size_t OFF_SKEY   = 24908032;  // 1024 (int)
static const size_t OFF_SPOS   = 24909056;  // 1024 (int)
static const size_t OFF_BSTART = 24910080;  // 224 (int; use NVB+1)
// end ~24,910,304 floats = 99.6 MB (< proven 106.4 MB)

__device__ __forceinline__ float sigmf(float x) { return 1.f / (1.f + expf(-x)); }

__device__ __forceinline__ float wsum64(float x) {
#pragma unroll
  for (int m = 1; m < 64; m <<= 1) x += __shfl_xor(x, m, 64);
  return x;
}

__device__ __forceinline__ unsigned short bf16r(float x) {
  uint32_t b = __float_as_uint(x);
  uint32_t r = (b + 0x7fffu + ((b >> 16) & 1u)) >> 16;
  return (unsigned short)r;
}
__device__ __forceinline__ float bflo(unsigned u) { return __uint_as_float(u << 16); }
__device__ __forceinline__ float bfhi(unsigned u) { return __uint_as_float(u & 0xffff0000u); }

// coherent (fabric-point) accessors: bypass L1/L2, per-word coherent across XCDs
__device__ __forceinline__ float cload(const float* p) {
  return __hip_atomic_load((float*)p, __ATOMIC_RELAXED, __HIP_MEMORY_SCOPE_AGENT);
}
__device__ __forceinline__ void cstore(float* p, float v) {
  __hip_atomic_store(p, v, __ATOMIC_RELAXED, __HIP_MEMORY_SCOPE_AGENT);
}
__device__ __forceinline__ int cloadi(const int* p) {
  return __hip_atomic_load((int*)p, __ATOMIC_RELAXED, __HIP_MEMORY_SCOPE_AGENT);
}
__device__ __forceinline__ void cstorei(int* p, int v) {
  __hip_atomic_store(p, v, __ATOMIC_RELAXED, __HIP_MEMORY_SCOPE_AGENT);
}

// device-wide barrier, zero cache maintenance (proven in rounds 2-3)
__device__ __forceinline__ void gridbar(float* ws) {
  int* bar = (int*)(ws + OFF_BAR);
  __syncthreads();
  if (threadIdx.x == 0) {
    asm volatile("s_waitcnt vmcnt(0) lgkmcnt(0)" ::: "memory");
    int g = __hip_atomic_load(&bar[32], __ATOMIC_RELAXED, __HIP_MEMORY_SCOPE_AGENT);
    int old = __hip_atomic_fetch_add(&bar[0], 1, __ATOMIC_RELAXED, __HIP_MEMORY_SCOPE_AGENT);
    if (old == NBLK - 1) {
      __hip_atomic_store(&bar[0], 0, __ATOMIC_RELAXED, __HIP_MEMORY_SCOPE_AGENT);
      __hip_atomic_store(&bar[32], g + 1, __ATOMIC_RELAXED, __HIP_MEMORY_SCOPE_AGENT);
    } else {
      while (__hip_atomic_load(&bar[32], __ATOMIC_RELAXED, __HIP_MEMORY_SCOPE_AGENT) == g)
        __builtin_amdgcn_s_sleep(2);
    }
  }
  __syncthreads();
}

// ---------------- P1: gather embeddings, transposes ----------------
__global__ __launch_bounds__(256) void k_setup(float* __restrict__ ws, const int* __restrict__ ids,
                                               const float* __restrict__ embt, const float* __restrict__ ewf,
                                               const float* __restrict__ ewb, const float* __restrict__ eap) {
  int idx = blockIdx.x * 256 + threadIdx.x;
  if (idx < 131072) {
    int tt = idx >> 7, e = idx & 127;
    int id = ids[tt]; if (id >= VOCAB) id = UNK;
    ws[OFF_EMB + idx] = embt[(size_t)id * 128 + e];
  } else if (idx < 212992) {
    int i = idx - 131072;
    int k = i / 640, g = i - (i / 640) * 640;
    ws[OFF_WIHT_F + i] = ewf[(size_t)g * 128 + k];
  } else if (idx < 294912) {
    int i = idx - 212992;
    int k = i / 640, g = i - (i / 640) * 640;
    ws[OFF_WIHT_B + i] = ewb[(size_t)g * 128 + k];
  } else if (idx < 397312) {
    int i = idx - 294912;
    int k = i / 320, j = i - (i / 320) * 320;
    ws[OFF_WTE + i] = eap[(size_t)j * 320 + k];
  }
}

// ---------------- P2: encoder x-part gates ----------------
__global__ __launch_bounds__(256) void k_xg(float* __restrict__ ws,
                                            const float* __restrict__ bif, const float* __restrict__ bhf,
                                            const float* __restrict__ bib, const float* __restrict__ bhb) {
  int idx = blockIdx.x * 256 + threadIdx.x;
  int d = idx / 655360;
  int r = idx - d * 655360;
  int tt = r / 640, g = r - (r / 640) * 640;
  const float* wT = ws + (d ? OFF_WIHT_B : OFF_WIHT_F);
  const float* er = ws + OFF_EMB + (size_t)(d ? (1023 - tt) : tt) * 128;
  float acc = d ? (bib[g] + bhb[g]) : (bif[g] + bhf[g]);
#pragma unroll 4
  for (int k = 0; k < 128; ++k) acc += er[k] * wT[(size_t)k * 640 + g];
  ws[OFF_XG + idx] = acc;
}

// ---------------- P3: sequential bi-LSTM encoder ----------------
__global__ __launch_bounds__(512) void k_encoder(float* __restrict__ ws, const float* __restrict__ whh_f,
                                                 const float* __restrict__ whh_b) {
  const int dir = blockIdx.x;
  const int tid = threadIdx.x;
  const float* whh = dir ? whh_b : whh_f;
  const float* xg = ws + OFF_XG + (size_t)dir * 655360;
  __shared__ float hbuf[160];
  __shared__ float part[4][640];
  const int q = tid & 127, kg = tid >> 7, ks = kg * 40;
  float w[5][40];
#pragma unroll
  for (int j = 0; j < 5; ++j)
#pragma unroll
    for (int i = 0; i < 40; ++i)
      w[j][i] = whh[(size_t)(5 * q + j) * 160 + ks + i];
  float cst = 0.f;
  if (tid < 160) hbuf[tid] = 0.f;
  __syncthreads();
  for (int t = 0; t < 1024; ++t) {
    float acc[5] = {0.f, 0.f, 0.f, 0.f, 0.f};
#pragma unroll
    for (int i4 = 0; i4 < 10; ++i4) {
      float4 h4 = *(const float4*)&hbuf[ks + i4 * 4];
#pragma unroll
      for (int j = 0; j < 5; ++j)
        acc[j] += w[j][i4 * 4 + 0] * h4.x + w[j][i4 * 4 + 1] * h4.y + w[j][i4 * 4 + 2] * h4.z + w[j][i4 * 4 + 3] * h4.w;
    }
#pragma unroll
    for (int j = 0; j < 5; ++j) part[kg][5 * q + j] = acc[j];
    __syncthreads();
    if (tid < 160) {
      float gi = xg[(size_t)t * 640 + tid];
      float gf = xg[(size_t)t * 640 + 160 + tid];
      float gg = xg[(size_t)t * 640 + 320 + tid];
      float go = xg[(size_t)t * 640 + 480 + tid];
#pragma unroll
      for (int k2 = 0; k2 < 4; ++k2) {
        gi += part[k2][tid]; gf += part[k2][160 + tid];
        gg += part[k2][320 + tid]; go += part[k2][480 + tid];
      }
      cst = sigmf(gf) * cst + sigmf(gi) * tanhf(gg);
      float hn = sigmf(go) * tanhf(cst);
      hbuf[tid] = hn;
      int trow = dir ? (1023 - t) : t;
      ws[OFF_ENCH + (size_t)trow * 320 + dir * 160 + tid] = hn;
    }
    __syncthreads();
  }
  if (tid < 160) ws[OFF_H0 + dir * 160 + tid] = hbuf[tid];
}

// ---------------- P4: enc_proj_h ----------------
__global__ __launch_bounds__(256) void k_encproj(float* __restrict__ ws) {
  int idx = blockIdx.x * 256 + threadIdx.x;
  int s = idx / 320, j = idx - (idx / 320) * 320;
  const float* er = ws + OFF_ENCH + (size_t)s * 320;
  const float* wt = ws + OFF_WTE;
  float acc = 0.f;
#pragma unroll 4
  for (int k = 0; k < 320; ++k) acc += er[k] * wt[(size_t)k * 320 + j];
  ws[OFF_EPH + idx] = acc;
}

// ---------------- P5: W_T = bf16(tanh(embedding @ vocab_proj)), per-block-contiguous ----------------
// Layout: uint4[vb][k4][rl]; element (vb,k4,rl) packs features [8k4,8k4+8) of vocab
// row vb*256+rl. Runs AFTER encoder/encproj (overlays dead EMB/WIHT/WTE/XG).
__global__ __launch_bounds__(256) void k_outproj(const float* __restrict__ embt, const float* __restrict__ vp,
                                                 float* __restrict__ ws) {
  __shared__ float As[64][128];
  __shared__ float Bs[128][64];
  __shared__ unsigned T[32][64];
  const int tid = threadIdx.x;
  const int v0 = blockIdx.x * 64, n0 = blockIdx.y * 64;
  for (int c = 0; c < 32; ++c) {
    int idx = c * 256 + tid;
    int m = idx >> 7, k = idx & 127;
    int v = v0 + m;
    As[m][k] = (v < VOCAB) ? embt[(size_t)v * 128 + k] : 0.f;
    int k2 = idx >> 6, n = idx & 63;
    Bs[k2][n] = vp[(size_t)k2 * 960 + n0 + n];
  }
  __syncthreads();
  const int mi = tid >> 4, ni = tid & 15;
  float acc[4][4] = {};
  for (int k = 0; k < 128; ++k) {
    float a0 = As[mi * 4 + 0][k], a1 = As[mi * 4 + 1][k], a2 = As[mi * 4 + 2][k], a3 = As[mi * 4 + 3][k];
    float4 b = *(const float4*)&Bs[k][ni * 4];
    acc[0][0] += a0 * b.x; acc[0][1] += a0 * b.y; acc[0][2] += a0 * b.z; acc[0][3] += a0 * b.w;
    acc[1][0] += a1 * b.x; acc[1][1] += a1 * b.y; acc[1][2] += a1 * b.z; acc[1][3] += a1 * b.w;
    acc[2][0] += a2 * b.x; acc[2][1] += a2 * b.y; acc[2][2] += a2 * b.z; acc[2][3] += a2 * b.w;
    acc[3][0] += a3 * b.x; acc[3][1] += a3 * b.y; acc[3][2] += a3 * b.z; acc[3][3] += a3 * b.w;
  }
  // T[fp_local][row_local]: packed bf16 pair for features (n0+2fp_l, n0+2fp_l+1)
#pragma unroll
  for (int i = 0; i < 4; ++i) {
    unsigned p0 = (unsigned)bf16r(tanhf(acc[i][0])) | ((unsigned)bf16r(tanhf(acc[i][1])) << 16);
    unsigned p1 = (unsigned)bf16r(tanhf(acc[i][2])) | ((unsigned)bf16r(tanhf(acc[i][3])) << 16);
    T[2 * ni][mi * 4 + i] = p0;
    T[2 * ni + 1][mi * 4 + i] = p1;
  }
  __syncthreads();
  uint4* WT4 = (uint4*)(ws + OFF_WT);
  const int vb = blockIdx.x >> 2;          // decode vocab-block
  const int rb = (blockIdx.x & 3) * 64;    // row offset within vb
  const int k4b = n0 >> 3;                 // global k4 base (8 k4s per tile)
#pragma unroll
  for (int i = 0; i < 2; ++i) {
    int flat = i * 256 + tid;              // 0..511 = 8 k4 x 64 cols
    int k4l = flat >> 6, col = flat & 63;
    uint4 u;
    u.x = T[4 * k4l + 0][col];
    u.y = T[4 * k4l + 1][col];
    u.z = T[4 * k4l + 2][col];
    u.w = T[4 * k4l + 3][col];
    WT4[(size_t)vb * (K4N * 256) + (size_t)(k4b + k4l) * 256 + rb + col] = u;
  }
}

// ---------------- P6: sort ids + slice table + state init ----------------
__global__ __launch_bounds__(512) void k_sort(float* __restrict__ ws, const int* __restrict__ ids) {
  __shared__ int sk[1024], sp[1024];
  const int tid = threadIdx.x;
  for (int j = tid; j < 1024; j += 512) { sk[j] = ids[j]; sp[j] = j; }
  __syncthreads();
  for (int k = 2; k <= 1024; k <<= 1)
    for (int j = k >> 1; j > 0; j >>= 1) {
      for (int i = tid; i < 1024; i += 512) {
        int ixj = i ^ j;
        if (ixj > i) {
          bool up = ((i & k) == 0);
          int a = sk[i], b2 = sk[ixj];
          if (up ? (a > b2) : (a < b2)) {
            sk[i] = b2; sk[ixj] = a;
            int pa = sp[i]; sp[i] = sp[ixj]; sp[ixj] = pa;
          }
        }
      }
      __syncthreads();
    }
  int* BST = (int*)(ws + OFF_BSTART);
  int* SK = (int*)(ws + OFF_SKEY);
  int* SP = (int*)(ws + OFF_SPOS);
  for (int j = tid; j < 1024; j += 512) {
    SK[j] = sk[j]; SP[j] = sp[j];
    int o1 = sk[j] >> 8;                       // vocab-block index (256 rows/block)
    int o0 = (j == 0) ? -1 : (sk[j - 1] >> 8);
    for (int o = o0 + 1; o <= o1; ++o) BST[o] = j;
  }
  if (tid < 256) {                             // neutral partials for non-vocab blocks
    ws[OFF_AVAL + tid] = -1e30f;
    ((int*)(ws + OFF_AIDX))[tid] = 0;
    ws[OFF_BM + tid] = -1e30f;
    ws[OFF_BS + tid] = 0.f;
  }
  if (tid == 0) {
    int olast = sk[1023] >> 8;
    for (int o = olast + 1; o <= NVB; ++o) BST[o] = 1024;
    int* bar = (int*)(ws + OFF_BAR);
    bar[0] = 0; bar[32] = 0;
  }
}

// ---------------- persistent decode ----------------
// Blocks 0..15: enc attention; 16: dec attention; 17..213: vocab GEMV (256 rows each,
// 2-way k-split over 512 threads, uint4 streams); 214..255: barrier-only.
__global__ __launch_bounds__(512) void k_decode(float* __restrict__ ws, float* __restrict__ out,
    const float* __restrict__ embt,
    const float* __restrict__ dwih, const float* __restrict__ dwhh,
    const float* __restrict__ dbih, const float* __restrict__ dbhh,
    const float* __restrict__ dap, const float* __restrict__ sw,
    const float* __restrict__ sb, const float* __restrict__ ob) {
  const int b = blockIdx.x, tid = threadIdx.x;
  const int l = tid & 63, w = tid >> 6;
  const int rl = tid & 255, half = tid >> 8;
  const int vb = b - VB0;
  const bool isv = (vb >= 0) && (vb < NVB);
  const int vrow = isv ? (vb * 256 + rl) : 0;
  const bool myrow = isv && (vrow < VOCAB);
  const uint4* WTb = ((const uint4*)(ws + OFF_WT)) + (size_t)(isv ? vb : 0) * (K4N * 256) + rl;

  __shared__ __align__(16) float hL[320];
  __shared__ float cL[320];
  __shared__ __align__(16) float concatL[960];
  __shared__ float logitsL[256];
  __shared__ float p0L[256], p1L[256];
  __shared__ float tauL[4], cumL[4];
  __shared__ float redA[512], redB[512];
  __shared__ int   redI[512];
  __shared__ float attnL[64], dsL[128], daL[128], hpL[320];

  if (tid < 320) { hL[tid] = ws[OFF_H0 + tid]; cL[tid] = 0.f; }
  if (tid < 4) cumL[tid] = 0.f;
  __syncthreads();

  for (int t = 0; t < TDEC; ++t) {
    // ======= phase A: token argmax (replicated) + gate rows (5 per block) =======
    int token = 0;
    if (t > 0) {
      float av = -1e30f; int ai = 0;
      if (tid < 256) { av = cload(&ws[OFF_AVAL + tid]); ai = cloadi(((const int*)(ws + OFF_AIDX)) + tid); }
      redA[tid] = av; redI[tid] = ai;
      __syncthreads();
      for (int off = 256; off > 0; off >>= 1) {
        if (tid < off) {
          float v2 = redA[tid + off]; int i2 = redI[tid + off];
          if (v2 > redA[tid] || (v2 == redA[tid] && i2 < redI[tid])) { redA[tid] = v2; redI[tid] = i2; }
        }
        __syncthreads();
      }
      token = redI[0];
    }
    int tokm = (token >= VOCAB) ? UNK : token;
    if (w < 5) {  // gate rows 5b..5b+4, one per warp
      const int r = 5 * b + w;
      float acc = dwih[(size_t)r * 128 + l] * embt[(size_t)tokm * 128 + l]
                + dwih[(size_t)r * 128 + 64 + l] * embt[(size_t)tokm * 128 + 64 + l];
#pragma unroll
      for (int c = 0; c < 5; ++c) acc += dwhh[(size_t)r * 320 + c * 64 + l] * hL[c * 64 + l];
      acc = wsum64(acc);
      if (l == 0) cstore(&ws[OFF_GATES + r], acc + dbih[r] + dbhh[r]);
    }
    gridbar(ws);

    // ======= phase B: replicated h,c + score rows + hpar partials =======
    if (tid < 320) {
      float gi = cload(&ws[OFF_GATES + tid]);
      float gf = cload(&ws[OFF_GATES + 320 + tid]);
      float gg = cload(&ws[OFF_GATES + 640 + tid]);
      float go = cload(&ws[OFF_GATES + 960 + tid]);
      float c = sigmf(gf) * cL[tid] + sigmf(gi) * tanhf(gg);
      cL[tid] = c;
      float hn = sigmf(go) * tanhf(c);
      hL[tid] = hn;
      if (b == 16) ws[OFF_DECBUF + (size_t)t * 320 + tid] = hn;  // private to block 16
    }
    __syncthreads();
    if (w < 4) {  // score rows 4b..4b+3
      const int srow = 4 * b + w;
      const float* er = ws + OFF_EPH + (size_t)srow * 320;
      float acc = 0.f;
#pragma unroll
      for (int c = 0; c < 5; ++c) acc += er[c * 64 + l] * hL[c * 64 + l];
      acc = wsum64(acc);
      float tau = (t == 0) ? acc : expf(acc) / cumL[w];
      if (l == 0) {
        tauL[w] = tau;
        cstore(&ws[OFF_TEMP + srow], tau);
        cumL[w] += acc;
      }
    }
    if (b < 8 && tid < 320) {  // hpar partials (split over inner dim, 8 x 40)
      float acc = 0.f;
#pragma unroll 8
      for (int ii = 0; ii < 40; ++ii) {
        int i = b * 40 + ii;
        acc += hL[i] * dap[(size_t)i * 320 + tid];
      }
      cstore(&ws[OFF_HPAR + b * 320 + tid], acc);
    }
    __syncthreads();
    if (tid == 0) {
      float m4 = fmaxf(fmaxf(tauL[0], tauL[1]), fmaxf(tauL[2], tauL[3]));
      float s4 = expf(tauL[0] - m4) + expf(tauL[1] - m4) + expf(tauL[2] - m4) + expf(tauL[3] - m4);
      cstore(&ws[OFF_PMS + 2 * b], m4);
      cstore(&ws[OFF_PMS + 2 * b + 1], s4);
    }
    gridbar(ws);

    // ======= phase C: attention (blocks 0..16) | GEMV h-part (vocab blocks) =======
    float ga0 = 0.f, ga1 = 0.f;
    if (b < 16) {
      float m = -1e30f, s = 0.f;
      if (tid < 256) { m = cload(&ws[OFF_PMS + 2 * tid]); s = cload(&ws[OFF_PMS + 2 * tid + 1]); }
      redA[tid] = m; redB[tid] = s;
      __syncthreads();
      for (int off = 256; off > 0; off >>= 1) {
        if (tid < off) {
          float m1 = redA[tid], m2 = redA[tid + off];
          float mx = fmaxf(m1, m2);
          redB[tid] = redB[tid] * expf(m1 - mx) + redB[tid + off] * expf(m2 - mx);
          redA[tid] = mx;
        }
        __syncthreads();
      }
      const float M = redA[0], S = redB[0];
      __syncthreads();
      if (tid < 64) {
        float a = expf(cload(&ws[OFF_TEMP + 64 * b + tid]) - M) / S;
        attnL[tid] = a;
        cstore(&ws[OFF_ATTN + 64 * b + tid], a);
      }
      __syncthreads();
      if (tid < 320) {
        float acc = 0.f;
        const float* eh = ws + OFF_ENCH + (size_t)(64 * b) * 320 + tid;
#pragma unroll 4
        for (int k2 = 0; k2 < 64; ++k2) acc += attnL[k2] * eh[(size_t)k2 * 320];
        cstore(&ws[OFF_CPAR + b * 320 + tid], acc);
      }
    } else if (b == 16) {
      if (tid < 320) {
        float a = 0.f;
#pragma unroll
        for (int q = 0; q < 8; ++q) a += cload(&ws[OFF_HPAR + q * 320 + tid]);
        hpL[tid] = a;
      }
      __syncthreads();
      float hpv[5];
#pragma unroll
      for (int c = 0; c < 5; ++c) hpv[c] = hpL[c * 64 + l];
#pragma unroll
      for (int k2 = 0; k2 < 13; ++k2) {
        int tp = w + 8 * k2;
        if (tp < t) {
          float acc = 0.f;
#pragma unroll
          for (int c = 0; c < 5; ++c) acc += hpv[c] * ws[OFF_DECBUF + (size_t)tp * 320 + c * 64 + l];
          acc = wsum64(acc);
          if (l == 0) dsL[tp] = acc;
        }
      }
      __syncthreads();
      float dv = -1e30f;
      if (tid < 128) { dv = (tid < t) ? dsL[tid] : -1e30f; redA[tid] = dv; }
      __syncthreads();
      for (int off = 64; off > 0; off >>= 1) { if (tid < off) redA[tid] = fmaxf(redA[tid], redA[tid + off]); __syncthreads(); }
      float dmx = redA[0];
      __syncthreads();
      float de = (tid < 128) ? expf(dv - dmx) : 0.f;
      if (tid < 128) redA[tid] = de;
      __syncthreads();
      for (int off = 64; off > 0; off >>= 1) { if (tid < off) redA[tid] += redA[tid + off]; __syncthreads(); }
      float dS = redA[0];
      __syncthreads();
      if (tid < 128) daL[tid] = de / dS;
      __syncthreads();
      if (tid < 320) {
        float acc = 0.f;
        for (int tp = 0; tp < t; ++tp) acc += daL[tp] * ws[OFF_DECBUF + (size_t)tp * 320 + tid];
        cstore(&ws[OFF_DCTX + tid], (t == 0) ? 0.f : acc);
      }
    } else if (isv) {
      // h-dependent k4s (features < 320): half 0 -> k4 0..19, half 1 -> k4 20..39
      const int c0 = half ? 20 : 0;
#pragma unroll 10
      for (int k4 = c0; k4 < c0 + 20; ++k4) {
        uint4 u = WTb[(size_t)k4 * 256];
        float4 fa = *(const float4*)&hL[8 * k4];
        float4 fb = *(const float4*)&hL[8 * k4 + 4];
        ga0 += bflo(u.x) * fa.x + bflo(u.y) * fa.z + bflo(u.z) * fb.x + bflo(u.w) * fb.z;
        ga1 += bfhi(u.x) * fa.y + bfhi(u.y) * fa.w + bfhi(u.z) * fb.y + bfhi(u.w) * fb.w;
      }
    }
    gridbar(ws);

    // ======= phase D: concat + GEMV ctx-part + block softmax partial; pc on block 0 =======
    if (isv || b == 0) {
      if (tid < 320) {
        float e = 0.f;
#pragma unroll
        for (int g2 = 0; g2 < 16; ++g2) e += cload(&ws[OFF_CPAR + g2 * 320 + tid]);
        concatL[tid] = hL[tid];
        concatL[320 + tid] = e;
        concatL[640 + tid] = cload(&ws[OFF_DCTX + tid]);
      }
    }
    __syncthreads();
    if (b == 0 && w == 0) {
      float acc = 0.f;
#pragma unroll
      for (int c = 0; c < 15; ++c) acc += sw[c * 64 + l] * concatL[c * 64 + l];
      acc = wsum64(acc);
      if (l == 0) cstore(&ws[OFF_PC], 1.f / (1.f + expf(-(acc + sb[0]))));
    }
    if (isv) {
      // ctx-dependent k4s: half 0 -> 40..79, half 1 -> 80..119
      const int d0 = half ? 80 : 40;
#pragma unroll 8
      for (int k4 = d0; k4 < d0 + 40; ++k4) {
        uint4 u = WTb[(size_t)k4 * 256];
        float4 fa = *(const float4*)&concatL[8 * k4];
        float4 fb = *(const float4*)&concatL[8 * k4 + 4];
        ga0 += bflo(u.x) * fa.x + bflo(u.y) * fa.z + bflo(u.z) * fb.x + bflo(u.w) * fb.z;
        ga1 += bfhi(u.x) * fa.y + bfhi(u.y) * fa.w + bfhi(u.z) * fb.y + bfhi(u.w) * fb.w;
      }
      if (half) p1L[rl] = ga0 + ga1; else p0L[rl] = ga0 + ga1;
    }
    __syncthreads();
    float lm = -1e30f, ls = 0.f;
    if (isv && tid < 256) {
      float lv = myrow ? (p0L[tid] + p1L[tid] + ob[vrow]) : -1e30f;
      logitsL[tid] = lv;
      if (lv > -1e29f) { lm = lv; ls = 1.f; }
    }
    redA[tid] = lm; redB[tid] = ls;
    __syncthreads();
    for (int off = 256; off > 0; off >>= 1) {
      if (tid < off) {
        float m1 = redA[tid], m2 = redA[tid + off];
        float mx = fmaxf(m1, m2);
        redB[tid] = redB[tid] * expf(m1 - mx) + redB[tid + off] * expf(m2 - mx);
        redA[tid] = mx;
      }
      __syncthreads();
    }
    if (isv && tid == 0) { cstore(&ws[OFF_BM + vb], redA[0]); cstore(&ws[OFF_BS + vb], redB[0]); }
    gridbar(ws);

    // ======= phase E: global softmax combine + final + scatter + argmax (vocab blocks) =======
    if (isv) {
      float m = -1e30f, s = 0.f;
      if (tid < 256) { m = cload(&ws[OFF_BM + tid]); s = cload(&ws[OFF_BS + tid]); }
      redA[tid] = m; redB[tid] = s;
      __syncthreads();
      for (int off = 256; off > 0; off >>= 1) {
        if (tid < off) {
          float m1 = redA[tid], m2 = redA[tid + off];
          float mx = fmaxf(m1, m2);
          redB[tid] = redB[tid] * expf(m1 - mx) + redB[tid + off] * expf(m2 - mx);
          redA[tid] = mx;
        }
        __syncthreads();
      }
      const float M = redA[0], Sg = redB[0];
      const float pc = cload(&ws[OFF_PC]);
      const float scale = (1.f - pc) / Sg;
      __syncthreads();
      const int* BST = (const int*)(ws + OFF_BSTART);
      const int* SK = (const int*)(ws + OFF_SKEY);
      const int* SP = (const int*)(ws + OFF_SPOS);
      bool act = (tid < 256) && (vrow < VTOT);
      float val = -1e30f;
      if (act) {
        val = (vrow < VOCAB) ? scale * expf(logitsL[tid] - M) : 0.f;
        int jb = BST[vb], je = BST[vb + 1];
        for (int j = jb; j < je; ++j)
          if (SK[j] == vrow) val += pc * cload(&ws[OFF_ATTN + SP[j]]);
        out[(size_t)t * VTOT + vrow] = val;
      }
      redA[tid] = act ? val : -1e30f; redI[tid] = vrow;
      __syncthreads();
      for (int off = 256; off > 0; off >>= 1) {
        if (tid < off) {
          float v2 = redA[tid + off]; int i2 = redI[tid + off];
          if (v2 > redA[tid] || (v2 == redA[tid] && i2 < redI[tid])) { redA[tid] = v2; redI[tid] = i2; }
        }
        __syncthreads();
      }
      if (tid == 0) { cstore(&ws[OFF_AVAL + b], redA[0]); cstorei(((int*)(ws + OFF_AIDX)) + b, redI[0]); }
    }
    gridbar(ws);
  }
}

// ---------------- host ----------------
extern "C" void kernel_launch(void* const* d_in, const int* in_sizes, int n_in,
                              void* d_out, int out_size, void* d_ws, size_t ws_size,
                              hipStream_t stream) {
  const int*   ids  = (const int*)d_in[0];
  const float* embt = (const float*)d_in[1];
  const float* ewf  = (const float*)d_in[2];
  const float* ehf  = (const float*)d_in[3];
  const float* ebif = (const float*)d_in[4];
  const float* ebhf = (const float*)d_in[5];
  const float* ewb  = (const float*)d_in[6];
  const float* ehb  = (const float*)d_in[7];
  const float* ebib = (const float*)d_in[8];
  const float* ebhb = (const float*)d_in[9];
  const float* dwih = (const float*)d_in[10];
  const float* dwhh = (const float*)d_in[11];
  const float* dbih = (const float*)d_in[12];
  const float* dbhh = (const float*)d_in[13];
  const float* eap  = (const float*)d_in[14];
  const float* dap  = (const float*)d_in[15];
  const float* vp   = (const float*)d_in[16];
  const float* ob   = (const float*)d_in[17];
  const float* sw   = (const float*)d_in[18];
  const float* sb   = (const float*)d_in[19];
  float* out = (float*)d_out;
  float* ws  = (float*)d_ws;

  k_setup<<<1558, 256, 0, stream>>>(ws, ids, embt, ewf, ewb, eap);
  k_xg<<<5120, 256, 0, stream>>>(ws, ebif, ebhf, ebib, ebhb);
  k_encoder<<<2, 512, 0, stream>>>(ws, ehf, ehb);
  k_encproj<<<1280, 256, 0, stream>>>(ws);
  k_outproj<<<dim3(786, 15), 256, 0, stream>>>(embt, vp, ws);   // after encoder: overlays XG etc.
  k_sort<<<1, 512, 0, stream>>>(ws, ids);
  k_decode<<<NBLK, NTHR, 0, stream>>>(ws, out, embt, dwih, dwhh, dbih, dbhh, dap, sw, sb, ob);
}